// Round 9
// baseline (581.938 us; speedup 1.0000x reference)
//
#include <hip/hip_runtime.h>
#include <hip/hip_bf16.h>

typedef __attribute__((ext_vector_type(8))) short short8;
typedef __attribute__((ext_vector_type(4))) float f32x4;

#define DEVI static __device__ __forceinline__

constexpr int HID = 1024;
constexpr int BB = 4, LL = 4096;
constexpr int MROWS = BB * LL;   // 16384
constexpr int NCH = 64, TCH = 64;

// ---------------- ws layout ----------------
constexpr size_t ELN_EMB  = 0;
constexpr size_t ELN_WABO = 16777216;
constexpr size_t ELN_CW   = 19922944;
constexpr size_t ELN_F1   = 20971520;
constexpr size_t ELN_F2   = 25165824;
constexpr size_t ELN_PW   = 29360128;
constexpr size_t ELN_END  = 30408704;
constexpr size_t POOL_BYTES = ELN_END * 2;      // 60,817,408

constexpr size_t OFF_ABW = POOL_BYTES;
constexpr size_t OFF_H   = OFF_ABW + (size_t)MROWS*3072*2;
constexpr size_t OFF_U   = OFF_H  + (size_t)MROWS*1024*2;
constexpr size_t OFF_AGG = OFF_U  + (size_t)MROWS*1024*2;
constexpr size_t AG_ELEMS = (size_t)BB * NCH * HID;
constexpr size_t WS_NEEDED = OFF_AGG + AG_ELEMS * 4 * 3;     // 231,735,296 (proven fit)

// ---------------- helpers ----------------
DEVI unsigned short f2b(float x) {
  unsigned u = __float_as_uint(x);
  return (unsigned short)((u + 0x7fffu + ((u >> 16) & 1u)) >> 16);
}
DEVI float b2f(unsigned short u) { return __uint_as_float((unsigned)u << 16); }

DEVI float fast_tanh(float y) {
  y = fminf(fmaxf(y, -10.f), 10.f);
  float e = __expf(2.f * y);
  return (e - 1.f) / (e + 1.f);
}
DEVI float gelu_fast(float x) {
  float t = 0.7978845608028654f * (x + 0.044715f * x * x * x);
  return 0.5f * x * (1.f + fast_tanh(t));
}

DEVI void gload_lds16(const unsigned short* g, unsigned short* l) {
  __builtin_amdgcn_global_load_lds(
      (const __attribute__((address_space(1))) void*)g,
      (__attribute__((address_space(3))) void*)l, 16, 0, 0);
}
DEVI void sbar() { __builtin_amdgcn_s_barrier(); }

// ---------------- f32 -> bf16 conversion: emb + packed weights ----------------
constexpr long CH_EMB = 16777216 / 8;
constexpr long CH_W   = 1048576 / 8;
constexpr long CH_F   = 4194304 / 8;
constexpr long SEG1 = CH_EMB;
constexpr long SEG2 = SEG1 + CH_W;
constexpr long SEG3 = SEG2 + CH_W;
constexpr long SEG4 = SEG3 + CH_W;
constexpr long SEG5 = SEG4 + CH_W;
constexpr long SEG6 = SEG5 + CH_F;
constexpr long SEG7 = SEG6 + CH_F;
constexpr long SEG8 = SEG7 + CH_W;

__global__ __launch_bounds__(256) void convert_all(
    const float* __restrict__ emb, const float* __restrict__ wa,
    const float* __restrict__ wb,  const float* __restrict__ wo,
    const float* __restrict__ cw,  const float* __restrict__ f1,
    const float* __restrict__ f2,  const float* __restrict__ pw,
    unsigned short* __restrict__ dst) {
  const long stride = (long)gridDim.x * blockDim.x;
  for (long ck = (long)blockIdx.x * blockDim.x + threadIdx.x; ck < SEG8; ck += stride) {
    const float* s; size_t d;
    if (ck < SEG1)      { s = emb + (size_t)ck * 8;        d = ELN_EMB + (size_t)ck * 8; }
    else if (ck < SEG2) { s = wa + (size_t)(ck-SEG1) * 8;  d = ELN_WABO + (size_t)(ck-SEG1) * 8; }
    else if (ck < SEG3) { s = wb + (size_t)(ck-SEG2) * 8;  d = ELN_WABO + 1048576 + (size_t)(ck-SEG2) * 8; }
    else if (ck < SEG4) { s = wo + (size_t)(ck-SEG3) * 8;  d = ELN_WABO + 2097152 + (size_t)(ck-SEG3) * 8; }
    else if (ck < SEG5) { s = cw + (size_t)(ck-SEG4) * 8;  d = ELN_CW + (size_t)(ck-SEG4) * 8; }
    else if (ck < SEG6) { s = f1 + (size_t)(ck-SEG5) * 8;  d = ELN_F1 + (size_t)(ck-SEG5) * 8; }
    else if (ck < SEG7) { s = f2 + (size_t)(ck-SEG6) * 8;  d = ELN_F2 + (size_t)(ck-SEG6) * 8; }
    else                { s = pw + (size_t)(ck-SEG7) * 8;  d = ELN_PW + (size_t)(ck-SEG7) * 8; }
    float4 x = *(const float4*)s;
    float4 y = *(const float4*)(s + 4);
    short8 o;
    o[0]=(short)f2b(x.x); o[1]=(short)f2b(x.y); o[2]=(short)f2b(x.z); o[3]=(short)f2b(x.w);
    o[4]=(short)f2b(y.x); o[5]=(short)f2b(y.y); o[6]=(short)f2b(y.z); o[7]=(short)f2b(y.w);
    *(short8*)(dst + d) = o;
  }
}

// ---------------- 256x256 BK=32 GEMM, 4-buf LDS, counted vmcnt (T4) -----------
// LDS row r (128B) holds A(r, 32 cols) and B(r, 32 cols) interleaved in 8 16B
// slots; slot s holds col-block s^(r&7) (0..3 = A, 4..7 = B). Write side
// realizes the swizzle via pre-swizzled per-lane GLOBAL source; reads XOR back.
// Pipeline: 3-tile prefetch, vmcnt(8) per tile (4 loads/tile/wave), never 0.
// EPI: 0 abw (tanh cols<1024) | 1 z=hw*(acc+b+w) | 2 gelu | 3 acc+b+u | 4 +b->f32
template <int EPI>
__global__ __launch_bounds__(512) void gemm256(
    const unsigned short* __restrict__ A, const unsigned short* __restrict__ Bw,
    int K, int NT, int ldo, int addld,
    const float* __restrict__ biasA, const float* __restrict__ biasB,
    const float* __restrict__ biasW,
    const unsigned short* __restrict__ addB, const float* __restrict__ hw,
    float* __restrict__ outF, unsigned short* __restrict__ outB) {
  __shared__ alignas(16) unsigned short lds[4][16384];  // 4 bufs x (256 rows x 64 ushort)
  const int tid = threadIdx.x;
  const int lane = tid & 63, wave = tid >> 6;
  const int wr = wave >> 2, wc = wave & 3;
  const int arow0 = blockIdx.x * 256, bcol0 = blockIdx.y * 256;
  f32x4 acc[8][4] = {};
  const int fm = lane & 15, fg = lane >> 4;
  const int sA = (fg ^ (fm & 7)) * 8;          // A read slot (ushort off)
  const int sB = ((4 + fg) ^ (fm & 7)) * 8;    // B read slot

  // staging sources: thread stages one 16B slot of one row, 4 passes (64 rows each)
#define MKSRC(l)                                                                   \
  const unsigned short* src##l; {                                                  \
    const int row_ = (tid >> 3) + 64 * l;                                          \
    const int c_ = (tid & 7) ^ (row_ & 7);                                         \
    src##l = (c_ < 4) ? A + (size_t)(arow0 + row_) * K + c_ * 8                    \
                      : Bw + (size_t)(bcol0 + row_) * K + (c_ - 4) * 8; }
  MKSRC(0) MKSRC(1) MKSRC(2) MKSRC(3)
#undef MKSRC

#define STAGE(p, t) do { const int ko_ = (t) * 32;                                 \
    gload_lds16(src0 + ko_, &lds[p][tid * 8]);                                     \
    gload_lds16(src1 + ko_, &lds[p][tid * 8 + 4096]);                              \
    gload_lds16(src2 + ko_, &lds[p][tid * 8 + 8192]);                              \
    gload_lds16(src3 + ko_, &lds[p][tid * 8 + 12288]); } while (0)

  STAGE(0, 0);
  if (NT > 1) STAGE(1, 1);
  if (NT > 2) STAGE(2, 2);
  asm volatile("s_waitcnt vmcnt(8)" ::: "memory");   // tile 0 resident
  sbar();

  for (int t = 0; t < NT; ++t) {
    const int p = t & 3;
    const unsigned short* LA = &lds[p][(wr * 128 + fm) * 64];
    const unsigned short* LB = &lds[p][(wc * 64 + fm) * 64];
    short8 af[4], bf[4];
    // phase A: mh0 (issue prefetch for t+3 first)
    if (t + 3 < NT) STAGE((t + 3) & 3, t + 3);
#pragma unroll
    for (int n = 0; n < 4; ++n) bf[n] = *(const short8*)(LB + n * 1024 + sB);
#pragma unroll
    for (int m = 0; m < 4; ++m) af[m] = *(const short8*)(LA + m * 1024 + sA);
    __builtin_amdgcn_s_setprio(1);
#pragma unroll
    for (int m = 0; m < 4; ++m)
#pragma unroll
      for (int n = 0; n < 4; ++n)
        acc[m][n] = __builtin_amdgcn_mfma_f32_16x16x32_bf16(af[m], bf[n], acc[m][n], 0, 0, 0);
    __builtin_amdgcn_s_setprio(0);
    sbar();
    // phase B: mh1 (B fragments reused)
#pragma unroll
    for (int m = 0; m < 4; ++m) af[m] = *(const short8*)(LA + 4096 + m * 1024 + sA);
    __builtin_amdgcn_s_setprio(1);
#pragma unroll
    for (int m = 0; m < 4; ++m)
#pragma unroll
      for (int n = 0; n < 4; ++n)
        acc[4 + m][n] = __builtin_amdgcn_mfma_f32_16x16x32_bf16(af[m], bf[n], acc[4 + m][n], 0, 0, 0);
    __builtin_amdgcn_s_setprio(0);
    // counted drain: ensure tile t+1 resident; keep t+2/t+3 in flight
    const int nleft = NT - 2 - t;
    if (nleft >= 2)      asm volatile("s_waitcnt vmcnt(8)" ::: "memory");
    else if (nleft == 1) asm volatile("s_waitcnt vmcnt(4)" ::: "memory");
    else                 asm volatile("s_waitcnt vmcnt(0)" ::: "memory");
    sbar();
    __builtin_amdgcn_sched_barrier(0);
  }
#undef STAGE

  // epilogue: D row = (lane>>4)*4 + reg, col = lane&15 [m89-verified]
  const int crow = (lane >> 4) * 4, ccol = lane & 15;
#pragma unroll
  for (int m = 0; m < 8; ++m) {
    const int row0 = arow0 + wr * 128 + (m >> 2) * 64 + (m & 3) * 16 + crow;
#pragma unroll
    for (int n = 0; n < 4; ++n) {
      const int col = bcol0 + wc * 64 + n * 16 + ccol;
#pragma unroll
      for (int r = 0; r < 4; ++r) {
        const size_t orow = (size_t)(row0 + r);
        float x = acc[m][n][r];
        if constexpr (EPI == 0) {
          const int cb = col >> 10;
          const float* bp = (cb == 0) ? biasA : (cb == 1 ? biasB : biasW);
          x += bp[col & 1023];
          if (cb == 0) x = fast_tanh(x);
          outB[orow * 3072 + col] = f2b(x);
        } else if constexpr (EPI == 1) {
          x += biasA[col] + b2f(addB[orow * (size_t)addld + col]);
          x *= hw[col >> 6];
          outB[orow * (size_t)ldo + col] = f2b(x);
        } else if constexpr (EPI == 2) {
          x += biasA[col];
          outB[orow * (size_t)ldo + col] = f2b(gelu_fast(x));
        } else if constexpr (EPI == 3) {
          x += biasA[col] + b2f(addB[orow * (size_t)addld + col]);
          outB[orow * (size_t)ldo + col] = f2b(x);
        } else {
          outF[orow * (size_t)ldo + col] = x + biasA[col];
        }
      }
    }
  }
}

// ---------------- chunked affine scan over abw layout [M][3072] ----------------
__global__ __launch_bounds__(256) void scan_p1(const unsigned short* __restrict__ abw,
                                               float* __restrict__ agA,
                                               float* __restrict__ agB) {
  const int idx = blockIdx.x;
  const int cg = idx & 3, ch = (idx >> 2) & (NCH - 1), bb = idx >> 8;
  const int c = cg * 256 + threadIdx.x;
  const size_t base = ((size_t)bb * LL + (size_t)ch * TCH) * 3072 + c;
  float A = 1.f, Bg = 0.f;
#pragma unroll 4
  for (int t = 0; t < TCH; ++t) {
    float at = b2f(abw[base + (size_t)t * 3072]);
    float bt = b2f(abw[base + (size_t)t * 3072 + 1024]);
    Bg = fmaf(at, Bg, bt);
    A *= at;
  }
  const size_t o = ((size_t)bb * NCH + ch) * HID + c;
  agA[o] = A;
  agB[o] = Bg;
}

__global__ __launch_bounds__(256) void scan_p2(const float* __restrict__ agA,
                                               const float* __restrict__ agB,
                                               float* __restrict__ pre) {
  const int gid = blockIdx.x * 256 + threadIdx.x;
  const int bb = gid >> 10, c = gid & 1023;
  float h = 0.f;
  for (int ch = 0; ch < NCH; ++ch) {
    const size_t o = ((size_t)bb * NCH + ch) * HID + c;
    pre[o] = h;
    h = fmaf(agA[o], h, agB[o]);
  }
}

__global__ __launch_bounds__(256) void scan_p3(const unsigned short* __restrict__ abw,
                                               const float* __restrict__ pre,
                                               unsigned short* __restrict__ hout) {
  const int idx = blockIdx.x;
  const int cg = idx & 3, ch = (idx >> 2) & (NCH - 1), bb = idx >> 8;
  const int c = cg * 256 + threadIdx.x;
  const size_t base = ((size_t)bb * LL + (size_t)ch * TCH) * 3072 + c;
  const size_t hbase = ((size_t)bb * LL + (size_t)ch * TCH) * HID + c;
  float h = pre[((size_t)bb * NCH + ch) * HID + c];
#pragma unroll 4
  for (int t = 0; t < TCH; ++t) {
    float at = b2f(abw[base + (size_t)t * 3072]);
    float bt = b2f(abw[base + (size_t)t * 3072 + 1024]);
    h = fmaf(at, h, bt);
    hout[hbase + (size_t)t * HID] = f2b(h);
  }
}

// ---------------- u = z + layernorm(z); z in abw[.,0..1023] ----------------
__global__ __launch_bounds__(256) void ln_kernel(const unsigned short* __restrict__ abw,
                                                 const float* __restrict__ gam,
                                                 const float* __restrict__ bet,
                                                 unsigned short* __restrict__ u) {
  const int wave = threadIdx.x >> 6, lane = threadIdx.x & 63;
  const int row = blockIdx.x * 4 + wave;
  const unsigned short* zr = abw + (size_t)row * 3072 + lane * 16;
  short8 z0 = *(const short8*)zr;
  short8 z1 = *(const short8*)(zr + 8);
  float x[16];
#pragma unroll
  for (int e = 0; e < 8; ++e) {
    x[e]     = b2f((unsigned short)z0[e]);
    x[8 + e] = b2f((unsigned short)z1[e]);
  }
  float s = 0.f, s2 = 0.f;
#pragma unroll
  for (int e = 0; e < 16; ++e) { s += x[e]; s2 += x[e] * x[e]; }
#pragma unroll
  for (int off = 32; off > 0; off >>= 1) {
    s += __shfl_xor(s, off, 64);
    s2 += __shfl_xor(s2, off, 64);
  }
  const float mu = s * (1.f / 1024.f);
  const float var = s2 * (1.f / 1024.f) - mu * mu;
  const float rs = rsqrtf(var + 1e-5f);
  const float* gp = gam + lane * 16;
  const float* bp = bet + lane * 16;
  short8 o0, o1;
#pragma unroll
  for (int e = 0; e < 8; ++e) {
    float v0 = x[e]     + (x[e]     - mu) * rs * gp[e]     + bp[e];
    float v1 = x[8 + e] + (x[8 + e] - mu) * rs * gp[8 + e] + bp[8 + e];
    o0[e] = (short)f2b(v0);
    o1[e] = (short)f2b(v1);
  }
  unsigned short* ur = u + (size_t)row * HID + lane * 16;
  *(short8*)ur = o0;
  *(short8*)(ur + 8) = o1;
}

// ---------------- launch ----------------
extern "C" void kernel_launch(void* const* d_in, const int* in_sizes, int n_in,
                              void* d_out, int out_size, void* d_ws, size_t ws_size,
                              hipStream_t stream) {
  if (ws_size < WS_NEEDED) return;

  const float* emb   = (const float*)d_in[0];
  const float* Wa_w  = (const float*)d_in[1];
  const float* Wa_b  = (const float*)d_in[2];
  const float* Wb_w  = (const float*)d_in[3];
  const float* Wb_b  = (const float*)d_in[4];
  const float* Wo_w  = (const float*)d_in[5];
  const float* Wo_b  = (const float*)d_in[6];
  const float* C_w   = (const float*)d_in[7];
  const float* C_b   = (const float*)d_in[8];
  const float* ln_g  = (const float*)d_in[9];
  const float* ln_b  = (const float*)d_in[10];
  const float* f1_w  = (const float*)d_in[11];
  const float* f1_b  = (const float*)d_in[12];
  const float* f2_w  = (const float*)d_in[13];
  const float* f2_b  = (const float*)d_in[14];
  const float* p_w   = (const float*)d_in[15];
  const float* p_b   = (const float*)d_in[16];
  const float* headw = (const float*)d_in[17];

  char* ws = (char*)d_ws;
  unsigned short* bfp  = (unsigned short*)ws;
  unsigned short* abwB = (unsigned short*)(ws + OFF_ABW);
  unsigned short* hB   = (unsigned short*)(ws + OFF_H);
  unsigned short* uB   = (unsigned short*)(ws + OFF_U);
  unsigned short* ffnB = abwB;                  // ffn [M][4096] spans abw+h
  float* agA = (float*)(ws + OFF_AGG);
  float* agB = agA + AG_ELEMS;
  float* pre = agB + AG_ELEMS;

  convert_all<<<2048, 256, 0, stream>>>(emb, Wa_w, Wb_w, Wo_w, C_w, f1_w, f2_w, p_w, bfp);

  // abw = [tanh(emb@Wa^T+ba) | emb@Wb^T+bb | emb@Wo^T+bo]
  gemm256<0><<<dim3(64, 12), 512, 0, stream>>>(
      bfp + ELN_EMB, bfp + ELN_WABO, 1024, 32, 3072, 0,
      Wa_b, Wb_b, Wo_b, nullptr, nullptr, nullptr, abwB);

  scan_p1<<<BB * NCH * 4, 256, 0, stream>>>(abwB, agA, agB);
  scan_p2<<<16, 256, 0, stream>>>(agA, agB, pre);
  scan_p3<<<BB * NCH * 4, 256, 0, stream>>>(abwB, pre, hB);

  // z = hw * (h@C^T + cb + w)
  gemm256<1><<<dim3(64, 4), 512, 0, stream>>>(
      hB, bfp + ELN_CW, 1024, 32, 3072, 3072,
      C_b, nullptr, nullptr, abwB + 2048, headw, nullptr, abwB);

  ln_kernel<<<4096, 256, 0, stream>>>(abwB, ln_g, ln_b, uB);

  // ffn = gelu(u@f1^T + b1)
  gemm256<2><<<dim3(64, 16), 512, 0, stream>>>(
      uB, bfp + ELN_F1, 1024, 32, 4096, 0,
      f1_b, nullptr, nullptr, nullptr, nullptr, nullptr, ffnB);

  // v = ffn@f2^T + b2 + u  (in-place over u)
  gemm256<3><<<dim3(64, 4), 512, 0, stream>>>(
      ffnB, bfp + ELN_F2, 4096, 128, 1024, 1024,
      f2_b, nullptr, nullptr, uB, nullptr, nullptr, uB);

  // out = v@p^T + pb  (f32)
  gemm256<4><<<dim3(64, 4), 512, 0, stream>>>(
      uB, bfp + ELN_PW, 1024, 32, 1024, 0,
      p_b, nullptr, nullptr, nullptr, nullptr, (float*)d_out, nullptr);
}

// Round 10
// 563.038 us; speedup vs baseline: 1.0336x; 1.0336x over previous
//
#include <hip/hip_runtime.h>
#include <hip/hip_bf16.h>

typedef __attribute__((ext_vector_type(8))) short short8;
typedef __attribute__((ext_vector_type(4))) float f32x4;

#define DEVI static __device__ __forceinline__

constexpr int HID = 1024;
constexpr int BB = 4, LL = 4096;
constexpr int MROWS = BB * LL;   // 16384
constexpr int NCH = 64, TCH = 64;

// ---------------- ws layout ----------------
constexpr size_t ELN_EMB  = 0;
constexpr size_t ELN_WABO = 16777216;
constexpr size_t ELN_CW   = 19922944;
constexpr size_t ELN_F1   = 20971520;
constexpr size_t ELN_F2   = 25165824;
constexpr size_t ELN_PW   = 29360128;
constexpr size_t ELN_END  = 30408704;
constexpr size_t POOL_BYTES = ELN_END * 2;      // 60,817,408

constexpr size_t OFF_ABW = POOL_BYTES;
constexpr size_t OFF_H   = OFF_ABW + (size_t)MROWS*3072*2;
constexpr size_t OFF_U   = OFF_H  + (size_t)MROWS*1024*2;
constexpr size_t OFF_AGG = OFF_U  + (size_t)MROWS*1024*2;
constexpr size_t AG_ELEMS = (size_t)BB * NCH * HID;
constexpr size_t WS_NEEDED = OFF_AGG + AG_ELEMS * 4 * 3;     // 231,735,296 (proven fit)

// ---------------- helpers ----------------
DEVI unsigned short f2b(float x) {
  unsigned u = __float_as_uint(x);
  return (unsigned short)((u + 0x7fffu + ((u >> 16) & 1u)) >> 16);
}
DEVI float b2f(unsigned short u) { return __uint_as_float((unsigned)u << 16); }

DEVI float fast_tanh(float y) {
  y = fminf(fmaxf(y, -10.f), 10.f);
  float e = __expf(2.f * y);
  return (e - 1.f) / (e + 1.f);
}
DEVI float gelu_fast(float x) {
  float t = 0.7978845608028654f * (x + 0.044715f * x * x * x);
  return 0.5f * x * (1.f + fast_tanh(t));
}

DEVI void gload_lds16(const unsigned short* g, unsigned short* l) {
  __builtin_amdgcn_global_load_lds(
      (const __attribute__((address_space(1))) void*)g,
      (__attribute__((address_space(3))) void*)l, 16, 0, 0);
}
DEVI void sbar() { __builtin_amdgcn_s_barrier(); }

// ---------------- f32 -> bf16 conversion: emb + packed weights ----------------
constexpr long CH_EMB = 16777216 / 8;
constexpr long CH_W   = 1048576 / 8;
constexpr long CH_F   = 4194304 / 8;
constexpr long SEG1 = CH_EMB;
constexpr long SEG2 = SEG1 + CH_W;
constexpr long SEG3 = SEG2 + CH_W;
constexpr long SEG4 = SEG3 + CH_W;
constexpr long SEG5 = SEG4 + CH_W;
constexpr long SEG6 = SEG5 + CH_F;
constexpr long SEG7 = SEG6 + CH_F;
constexpr long SEG8 = SEG7 + CH_W;

__global__ __launch_bounds__(256) void convert_all(
    const float* __restrict__ emb, const float* __restrict__ wa,
    const float* __restrict__ wb,  const float* __restrict__ wo,
    const float* __restrict__ cw,  const float* __restrict__ f1,
    const float* __restrict__ f2,  const float* __restrict__ pw,
    unsigned short* __restrict__ dst) {
  const long stride = (long)gridDim.x * blockDim.x;
  for (long ck = (long)blockIdx.x * blockDim.x + threadIdx.x; ck < SEG8; ck += stride) {
    const float* s; size_t d;
    if (ck < SEG1)      { s = emb + (size_t)ck * 8;        d = ELN_EMB + (size_t)ck * 8; }
    else if (ck < SEG2) { s = wa + (size_t)(ck-SEG1) * 8;  d = ELN_WABO + (size_t)(ck-SEG1) * 8; }
    else if (ck < SEG3) { s = wb + (size_t)(ck-SEG2) * 8;  d = ELN_WABO + 1048576 + (size_t)(ck-SEG2) * 8; }
    else if (ck < SEG4) { s = wo + (size_t)(ck-SEG3) * 8;  d = ELN_WABO + 2097152 + (size_t)(ck-SEG3) * 8; }
    else if (ck < SEG5) { s = cw + (size_t)(ck-SEG4) * 8;  d = ELN_CW + (size_t)(ck-SEG4) * 8; }
    else if (ck < SEG6) { s = f1 + (size_t)(ck-SEG5) * 8;  d = ELN_F1 + (size_t)(ck-SEG5) * 8; }
    else if (ck < SEG7) { s = f2 + (size_t)(ck-SEG6) * 8;  d = ELN_F2 + (size_t)(ck-SEG6) * 8; }
    else                { s = pw + (size_t)(ck-SEG7) * 8;  d = ELN_PW + (size_t)(ck-SEG7) * 8; }
    float4 x = *(const float4*)s;
    float4 y = *(const float4*)(s + 4);
    short8 o;
    o[0]=(short)f2b(x.x); o[1]=(short)f2b(x.y); o[2]=(short)f2b(x.z); o[3]=(short)f2b(x.w);
    o[4]=(short)f2b(y.x); o[5]=(short)f2b(y.y); o[6]=(short)f2b(y.z); o[7]=(short)f2b(y.w);
    *(short8*)(dst + d) = o;
  }
}

// ---------------- 256x256 GEMM, true 8-phase schedule (T3+T4+T2+T5) ----------
// Iteration = 2 K-tiles (BK=64 each) = 8 phases. Phase = {ds_read quadrant
// (8 or 4 b128, B reused across mh pair) | 2 global_load_lds | 16 MFMA}.
// vmcnt(8) at even-phase ends ONLY (12 loads in flight steady, never drained).
// LDS [2 buf][2 ks][256 rows x 128B]; rows: 8x16B slots, slot s holds col-block
// s^(row&7) (0-3 = A's 32K, 4-7 = B's 32K). Stage = pre-swizzled global source.
// EPI: 0 abw (tanh cols<1024) | 1 z=hw*(acc+b+w) | 2 gelu | 3 acc+b+u | 4 +b->f32
template <int EPI>
__global__ __launch_bounds__(512) void gemm256(
    const unsigned short* __restrict__ A, const unsigned short* __restrict__ Bw,
    int K, int NITER, int ldo, int addld,
    const float* __restrict__ biasA, const float* __restrict__ biasB,
    const float* __restrict__ biasW,
    const unsigned short* __restrict__ addB, const float* __restrict__ hw,
    float* __restrict__ outF, unsigned short* __restrict__ outB) {
  __shared__ alignas(16) unsigned short lds[2][2][16384];  // [buf][ks][256*64]
  const int tid = threadIdx.x;
  const int lane = tid & 63, wave = tid >> 6;
  const int wr = wave >> 2, wc = wave & 3;
  const int arow0 = blockIdx.x * 256, bcol0 = blockIdx.y * 256;
  f32x4 acc[8][4] = {};
  const int fm = lane & 15, fg = lane >> 4;
  const int sA = (fg ^ (fm & 7)) * 8;
  const int sB = ((4 + fg) ^ (fm & 7)) * 8;
  const int NT = NITER * 2;

  // per-thread stage sources (pass l covers rows 64l..64l+63; c_ invariant in l)
#define MKSRC(l)                                                                   \
  const unsigned short* src##l; {                                                  \
    const int row_ = (tid >> 3) + 64 * l;                                          \
    const int c_ = (tid & 7) ^ (row_ & 7);                                         \
    src##l = (c_ < 4) ? A + (size_t)(arow0 + row_) * K + c_ * 8                    \
                      : Bw + (size_t)(bcol0 + row_) * K + (c_ - 4) * 8; }
  MKSRC(0) MKSRC(1) MKSRC(2) MKSRC(3)
#undef MKSRC

  // stage half of unit (tile kt, k-half ks) into lds[bf][ks]: 2 loads/thread
#define STG0(bf, ks, kt) do { const int ko_ = (kt) * 64 + (ks) * 32;               \
    gload_lds16(src0 + ko_, &lds[bf][ks][tid * 8]);                                \
    gload_lds16(src1 + ko_, &lds[bf][ks][4096 + tid * 8]); } while (0)
#define STG1(bf, ks, kt) do { const int ko_ = (kt) * 64 + (ks) * 32;               \
    gload_lds16(src2 + ko_, &lds[bf][ks][8192 + tid * 8]);                         \
    gload_lds16(src3 + ko_, &lds[bf][ks][12288 + tid * 8]); } while (0)

  short8 bfr[4];
  // phase: read quadrant (BUF,KS,MH), stage STG, 16 MFMA, optional vmcnt(8), barrier
#define PHASE(BUF, KS, MH, NEWB, STG, DOVM) do {                                   \
    const unsigned short* lab = &lds[BUF][KS][0];                                  \
    if (NEWB) {                                                                    \
      _Pragma("unroll") for (int n = 0; n < 4; ++n)                                \
        bfr[n] = *(const short8*)(lab + (wc * 64 + n * 16 + fm) * 64 + sB);        \
    }                                                                              \
    short8 af[4];                                                                  \
    _Pragma("unroll") for (int m = 0; m < 4; ++m)                                  \
      af[m] = *(const short8*)(lab + (wr * 128 + MH * 64 + m * 16 + fm) * 64 + sA);\
    STG;                                                                           \
    __builtin_amdgcn_s_setprio(1);                                                 \
    _Pragma("unroll") for (int m = 0; m < 4; ++m)                                  \
      _Pragma("unroll") for (int n = 0; n < 4; ++n)                                \
        acc[MH * 4 + m][n] = __builtin_amdgcn_mfma_f32_16x16x32_bf16(              \
            af[m], bfr[n], acc[MH * 4 + m][n], 0, 0, 0);                           \
    __builtin_amdgcn_s_setprio(0);                                                 \
    if (DOVM) asm volatile("s_waitcnt vmcnt(8)" ::: "memory");                     \
    sbar();                                                                        \
    __builtin_amdgcn_sched_barrier(0);                                             \
  } while (0)

  // prologue: units (0,k0),(0,k1),(1,k0) = 12 loads; retire (0,k0)'s 4
  STG0(0, 0, 0); STG1(0, 0, 0);
  STG0(0, 1, 0); STG1(0, 1, 0);
  STG0(1, 0, 1); STG1(1, 0, 1);
  asm volatile("s_waitcnt vmcnt(8)" ::: "memory");
  sbar();
  __builtin_amdgcn_sched_barrier(0);

  for (int it = 0; it < NITER; ++it) {
    const int t1 = 2 * it + 1;
    const int t2 = (2 * it + 2 < NT) ? 2 * it + 2 : 0;   // wrap: stale-but-safe
    const int t3 = (2 * it + 3 < NT) ? 2 * it + 3 : 1;
    PHASE(0, 0, 0, true,  STG0(1, 1, t1), false);  // P1
    PHASE(0, 0, 1, false, STG1(1, 1, t1), true);   // P2  vm: retires (t0,k1)
    PHASE(0, 1, 0, true,  STG0(0, 0, t2), false);  // P3
    PHASE(0, 1, 1, false, STG1(0, 0, t2), true);   // P4  vm: retires (t1,k0)
    PHASE(1, 0, 0, true,  STG0(0, 1, t2), false);  // P5
    PHASE(1, 0, 1, false, STG1(0, 1, t2), true);   // P6  vm: retires (t1,k1)
    PHASE(1, 1, 0, true,  STG0(1, 0, t3), false);  // P7
    PHASE(1, 1, 1, false, STG1(1, 0, t3), true);   // P8  vm: retires (t0+2,k0)
  }
#undef PHASE
#undef STG0
#undef STG1

  // epilogue: D row = (lane>>4)*4 + reg, col = lane&15 [m89-verified]
  const int crow = (lane >> 4) * 4, ccol = lane & 15;
#pragma unroll
  for (int m = 0; m < 8; ++m) {
    const int row0 = arow0 + wr * 128 + (m >> 2) * 64 + (m & 3) * 16 + crow;
#pragma unroll
    for (int n = 0; n < 4; ++n) {
      const int col = bcol0 + wc * 64 + n * 16 + ccol;
#pragma unroll
      for (int r = 0; r < 4; ++r) {
        const size_t orow = (size_t)(row0 + r);
        float x = acc[m][n][r];
        if constexpr (EPI == 0) {
          const int cb = col >> 10;
          const float* bp = (cb == 0) ? biasA : (cb == 1 ? biasB : biasW);
          x += bp[col & 1023];
          if (cb == 0) x = fast_tanh(x);
          outB[orow * 3072 + col] = f2b(x);
        } else if constexpr (EPI == 1) {
          x += biasA[col] + b2f(addB[orow * (size_t)addld + col]);
          x *= hw[col >> 6];
          outB[orow * (size_t)ldo + col] = f2b(x);
        } else if constexpr (EPI == 2) {
          x += biasA[col];
          outB[orow * (size_t)ldo + col] = f2b(gelu_fast(x));
        } else if constexpr (EPI == 3) {
          x += biasA[col] + b2f(addB[orow * (size_t)addld + col]);
          outB[orow * (size_t)ldo + col] = f2b(x);
        } else {
          outF[orow * (size_t)ldo + col] = x + biasA[col];
        }
      }
    }
  }
}

// ---------------- chunked affine scan over abw layout [M][3072] ----------------
__global__ __launch_bounds__(256) void scan_p1(const unsigned short* __restrict__ abw,
                                               float* __restrict__ agA,
                                               float* __restrict__ agB) {
  const int idx = blockIdx.x;
  const int cg = idx & 3, ch = (idx >> 2) & (NCH - 1), bb = idx >> 8;
  const int c = cg * 256 + threadIdx.x;
  const size_t base = ((size_t)bb * LL + (size_t)ch * TCH) * 3072 + c;
  float A = 1.f, Bg = 0.f;
#pragma unroll 4
  for (int t = 0; t < TCH; ++t) {
    float at = b2f(abw[base + (size_t)t * 3072]);
    float bt = b2f(abw[base + (size_t)t * 3072 + 1024]);
    Bg = fmaf(at, Bg, bt);
    A *= at;
  }
  const size_t o = ((size_t)bb * NCH + ch) * HID + c;
  agA[o] = A;
  agB[o] = Bg;
}

__global__ __launch_bounds__(256) void scan_p2(const float* __restrict__ agA,
                                               const float* __restrict__ agB,
                                               float* __restrict__ pre) {
  const int gid = blockIdx.x * 256 + threadIdx.x;
  const int bb = gid >> 10, c = gid & 1023;
  float h = 0.f;
  for (int ch = 0; ch < NCH; ++ch) {
    const size_t o = ((size_t)bb * NCH + ch) * HID + c;
    pre[o] = h;
    h = fmaf(agA[o], h, agB[o]);
  }
}

__global__ __launch_bounds__(256) void scan_p3(const unsigned short* __restrict__ abw,
                                               const float* __restrict__ pre,
                                               unsigned short* __restrict__ hout) {
  const int idx = blockIdx.x;
  const int cg = idx & 3, ch = (idx >> 2) & (NCH - 1), bb = idx >> 8;
  const int c = cg * 256 + threadIdx.x;
  const size_t base = ((size_t)bb * LL + (size_t)ch * TCH) * 3072 + c;
  const size_t hbase = ((size_t)bb * LL + (size_t)ch * TCH) * HID + c;
  float h = pre[((size_t)bb * NCH + ch) * HID + c];
#pragma unroll 4
  for (int t = 0; t < TCH; ++t) {
    float at = b2f(abw[base + (size_t)t * 3072]);
    float bt = b2f(abw[base + (size_t)t * 3072 + 1024]);
    h = fmaf(at, h, bt);
    hout[hbase + (size_t)t * HID] = f2b(h);
  }
}

// ---------------- u = z + layernorm(z); z in abw[.,0..1023] ----------------
__global__ __launch_bounds__(256) void ln_kernel(const unsigned short* __restrict__ abw,
                                                 const float* __restrict__ gam,
                                                 const float* __restrict__ bet,
                                                 unsigned short* __restrict__ u) {
  const int wave = threadIdx.x >> 6, lane = threadIdx.x & 63;
  const int row = blockIdx.x * 4 + wave;
  const unsigned short* zr = abw + (size_t)row * 3072 + lane * 16;
  short8 z0 = *(const short8*)zr;
  short8 z1 = *(const short8*)(zr + 8);
  float x[16];
#pragma unroll
  for (int e = 0; e < 8; ++e) {
    x[e]     = b2f((unsigned short)z0[e]);
    x[8 + e] = b2f((unsigned short)z1[e]);
  }
  float s = 0.f, s2 = 0.f;
#pragma unroll
  for (int e = 0; e < 16; ++e) { s += x[e]; s2 += x[e] * x[e]; }
#pragma unroll
  for (int off = 32; off > 0; off >>= 1) {
    s += __shfl_xor(s, off, 64);
    s2 += __shfl_xor(s2, off, 64);
  }
  const float mu = s * (1.f / 1024.f);
  const float var = s2 * (1.f / 1024.f) - mu * mu;
  const float rs = rsqrtf(var + 1e-5f);
  const float* gp = gam + lane * 16;
  const float* bp = bet + lane * 16;
  short8 o0, o1;
#pragma unroll
  for (int e = 0; e < 8; ++e) {
    float v0 = x[e]     + (x[e]     - mu) * rs * gp[e]     + bp[e];
    float v1 = x[8 + e] + (x[8 + e] - mu) * rs * gp[8 + e] + bp[8 + e];
    o0[e] = (short)f2b(v0);
    o1[e] = (short)f2b(v1);
  }
  unsigned short* ur = u + (size_t)row * HID + lane * 16;
  *(short8*)ur = o0;
  *(short8*)(ur + 8) = o1;
}

// ---------------- launch ----------------
extern "C" void kernel_launch(void* const* d_in, const int* in_sizes, int n_in,
                              void* d_out, int out_size, void* d_ws, size_t ws_size,
                              hipStream_t stream) {
  if (ws_size < WS_NEEDED) return;

  const float* emb   = (const float*)d_in[0];
  const float* Wa_w  = (const float*)d_in[1];
  const float* Wa_b  = (const float*)d_in[2];
  const float* Wb_w  = (const float*)d_in[3];
  const float* Wb_b  = (const float*)d_in[4];
  const float* Wo_w  = (const float*)d_in[5];
  const float* Wo_b  = (const float*)d_in[6];
  const float* C_w   = (const float*)d_in[7];
  const float* C_b   = (const float*)d_in[8];
  const float* ln_g  = (const float*)d_in[9];
  const float* ln_b  = (const float*)d_in[10];
  const float* f1_w  = (const float*)d_in[11];
  const float* f1_b  = (const float*)d_in[12];
  const float* f2_w  = (const float*)d_in[13];
  const float* f2_b  = (const float*)d_in[14];
  const float* p_w   = (const float*)d_in[15];
  const float* p_b   = (const float*)d_in[16];
  const float* headw = (const float*)d_in[17];

  char* ws = (char*)d_ws;
  unsigned short* bfp  = (unsigned short*)ws;
  unsigned short* abwB = (unsigned short*)(ws + OFF_ABW);
  unsigned short* hB   = (unsigned short*)(ws + OFF_H);
  unsigned short* uB   = (unsigned short*)(ws + OFF_U);
  unsigned short* ffnB = abwB;                  // ffn [M][4096] spans abw+h
  float* agA = (float*)(ws + OFF_AGG);
  float* agB = agA + AG_ELEMS;
  float* pre = agB + AG_ELEMS;

  convert_all<<<2048, 256, 0, stream>>>(emb, Wa_w, Wb_w, Wo_w, C_w, f1_w, f2_w, p_w, bfp);

  // abw = [tanh(emb@Wa^T+ba) | emb@Wb^T+bb | emb@Wo^T+bo]
  gemm256<0><<<dim3(64, 12), 512, 0, stream>>>(
      bfp + ELN_EMB, bfp + ELN_WABO, 1024, 8, 3072, 0,
      Wa_b, Wb_b, Wo_b, nullptr, nullptr, nullptr, abwB);

  scan_p1<<<BB * NCH * 4, 256, 0, stream>>>(abwB, agA, agB);
  scan_p2<<<16, 256, 0, stream>>>(agA, agB, pre);
  scan_p3<<<BB * NCH * 4, 256, 0, stream>>>(abwB, pre, hB);

  // z = hw * (h@C^T + cb + w)
  gemm256<1><<<dim3(64, 4), 512, 0, stream>>>(
      hB, bfp + ELN_CW, 1024, 8, 3072, 3072,
      C_b, nullptr, nullptr, abwB + 2048, headw, nullptr, abwB);

  ln_kernel<<<4096, 256, 0, stream>>>(abwB, ln_g, ln_b, uB);

  // ffn = gelu(u@f1^T + b1)
  gemm256<2><<<dim3(64, 16), 512, 0, stream>>>(
      uB, bfp + ELN_F1, 1024, 8, 4096, 0,
      f1_b, nullptr, nullptr, nullptr, nullptr, nullptr, ffnB);

  // v = ffn@f2^T + b2 + u  (in-place over u)
  gemm256<3><<<dim3(64, 4), 512, 0, stream>>>(
      ffnB, bfp + ELN_F2, 4096, 32, 1024, 1024,
      f2_b, nullptr, nullptr, uB, nullptr, nullptr, uB);

  // out = v@p^T + pb  (f32)
  gemm256<4><<<dim3(64, 4), 512, 0, stream>>>(
      uB, bfp + ELN_PW, 1024, 8, 1024, 0,
      p_b, nullptr, nullptr, nullptr, nullptr, (float*)d_out, nullptr);
}